// Round 11
// baseline (694.222 us; speedup 1.0000x reference)
//
#include <hip/hip_runtime.h>
#include <hip/hip_bf16.h>
#include <math.h>

#define N_ENT 100000
#define NB    50000
#define NE    200000
#define RR    8
#define NETOT (RR * NE)          // 1,600,000
#define NSEG  (RR * N_ENT)       // 800,000

typedef float f32x4  __attribute__((ext_vector_type(4)));
typedef short s16x8  __attribute__((ext_vector_type(8)));

__device__ __forceinline__ void split2(float x, short& h, short& l)
{
    unsigned uh = __float_as_uint(x) & 0xffff0000u;
    h = (short)(uh >> 16);
    float r = x - __uint_as_float(uh);
    l = (short)(__float_as_uint(r) >> 16);
}

// async global->LDS, 16B per lane (LDS dest = wave-uniform base + lane*16)
__device__ __forceinline__ void glds16(const float* g, float* l)
{
    __builtin_amdgcn_global_load_lds(
        (const __attribute__((address_space(1))) void*)g,
        (__attribute__((address_space(3))) void*)l, 16, 0, 0);
}

// ---------------- K pre-transform: Kt[r][o][d] = K[r][d][o], split hi/lo bf16 ---
__global__ __launch_bounds__(256)
void ktconv_k(const float* __restrict__ rel_k, const float* __restrict__ self_k,
              short* __restrict__ Kth, short* __restrict__ Ktl)
{
    const int r = blockIdx.x;              // 0..8, 8 == self
    const float* src = (r < 8) ? rel_k + (size_t)r * 16384 : self_k;
    short* oh = Kth + (size_t)r * 16384;
    short* ol = Ktl + (size_t)r * 16384;
    for (int i = 0; i < 64; ++i) {
        int ix = i * 256 + threadIdx.x;    // 0..16383
        int d = ix >> 7, o = ix & 127;
        short h, l;
        split2(src[ix], h, l);
        oh[o * 128 + d] = h;
        ol[o * 128 + d] = l;
    }
}

// ---------------- MFMA GEMM for the final self-kernel pass ----------------
template<bool FINAL, bool ACCUM>
__global__ __launch_bounds__(256)
void gemm_mfma_k(const float* __restrict__ X, int xstride,
                 const short* __restrict__ Kth, const short* __restrict__ Ktl,
                 int nkc,
                 const float* __restrict__ Abuf, const int* __restrict__ idx,
                 float* __restrict__ out, int nrows)
{
    __shared__ short Bh[128][136];
    __shared__ short Bl[128][136];

    const int t     = threadIdx.x;
    const int wv    = t >> 6;
    const int lane  = t & 63;
    const int col16 = lane & 15;
    const int g     = lane >> 4;
    const int rowbase = blockIdx.x * 128 + wv * 32;

    f32x4 acc[2][8];
#pragma unroll
    for (int m = 0; m < 2; ++m)
#pragma unroll
        for (int c = 0; c < 8; ++c) acc[m][c] = (f32x4){0.f, 0.f, 0.f, 0.f};

    for (int kc = 0; kc < nkc; ++kc) {
        __syncthreads();
        {
            const s16x8* gh = (const s16x8*)(Kth + (size_t)kc * 16384);
            const s16x8* gl = (const s16x8*)(Ktl + (size_t)kc * 16384);
#pragma unroll
            for (int i = 0; i < 8; ++i) {
                int f = t + i * 256;
                int o = f >> 4, c = f & 15;
                *(s16x8*)&Bh[o][c * 8] = gh[f];
                *(s16x8*)&Bl[o][c * 8] = gl[f];
            }
        }
        __syncthreads();

#pragma unroll
        for (int s = 0; s < 4; ++s) {
            s16x8 ah[2], al[2];
#pragma unroll
            for (int m = 0; m < 2; ++m) {
                int r = rowbase + m * 16 + col16;
                if (r > nrows - 1) r = nrows - 1;
                const float* xp = X + (size_t)r * xstride + kc * 128 + s * 32 + g * 8;
                float4 u0 = *(const float4*)xp;
                float4 u1 = *(const float4*)(xp + 4);
                float u[8] = {u0.x, u0.y, u0.z, u0.w, u1.x, u1.y, u1.z, u1.w};
#pragma unroll
                for (int j = 0; j < 8; ++j) {
                    short h, l; split2(u[j], h, l);
                    ah[m][j] = h; al[m][j] = l;
                }
            }
#pragma unroll
            for (int c = 0; c < 8; ++c) {
                s16x8 bh = *(const s16x8*)&Bh[c * 16 + col16][s * 32 + g * 8];
                s16x8 bl = *(const s16x8*)&Bl[c * 16 + col16][s * 32 + g * 8];
#pragma unroll
                for (int m = 0; m < 2; ++m) {
                    acc[m][c] = __builtin_amdgcn_mfma_f32_16x16x32_bf16(ah[m], bh, acc[m][c], 0, 0, 0);
                    acc[m][c] = __builtin_amdgcn_mfma_f32_16x16x32_bf16(ah[m], bl, acc[m][c], 0, 0, 0);
                    acc[m][c] = __builtin_amdgcn_mfma_f32_16x16x32_bf16(al[m], bh, acc[m][c], 0, 0, 0);
                }
            }
        }
    }

#pragma unroll
    for (int m = 0; m < 2; ++m) {
#pragma unroll
        for (int j = 0; j < 4; ++j) {
            int row = rowbase + m * 16 + g * 4 + j;
            if (row >= nrows) continue;
            float* op = out + (size_t)row * 128;
            if (FINAL) {
                int gi = idx[row];
                const float* Ar = Abuf + (size_t)gi * 128;
#pragma unroll
                for (int c = 0; c < 8; ++c) {
                    int col = c * 16 + col16;
                    float x = acc[m][c][j] + Ar[col];
                    op[col] = 1.f / (1.f + __expf(-x));
                }
            } else if (ACCUM) {
#pragma unroll
                for (int c = 0; c < 8; ++c) {
                    int col = c * 16 + col16;
                    op[col] += acc[m][c][j];
                }
            } else {
#pragma unroll
                for (int c = 0; c < 8; ++c)
                    op[c * 16 + col16] = acc[m][c][j];
            }
        }
    }
}

// ---------------- CSR build (1 edge/thread; count emits per-edge rank) --------
__global__ __launch_bounds__(256)
void count_k(const int* __restrict__ edge_src, unsigned* __restrict__ cnt,
             unsigned char* __restrict__ rank)
{
    int g = blockIdx.x * 256 + threadIdx.x;
    int r = g / NE;
    int src = edge_src[g];
    unsigned old = atomicAdd(&cnt[r * N_ENT + src], 1u);
    rank[g] = (unsigned char)old;
}

__global__ __launch_bounds__(256)
void scan1_k(const unsigned* __restrict__ cnt, unsigned* __restrict__ offs,
             unsigned* __restrict__ bsum)
{
    __shared__ unsigned s[256];
    const int t = threadIdx.x;
    const int base = blockIdx.x * 1024;
    unsigned v[4], sum = 0;
#pragma unroll
    for (int i = 0; i < 4; ++i) {
        int ix = base + t * 4 + i;
        v[i] = (ix < NSEG) ? cnt[ix] : 0u;
        sum += v[i];
    }
    s[t] = sum; __syncthreads();
    for (int off = 1; off < 256; off <<= 1) {
        unsigned x = (t >= off) ? s[t - off] : 0u;
        __syncthreads();
        s[t] += x;
        __syncthreads();
    }
    unsigned run = s[t] - sum;
#pragma unroll
    for (int i = 0; i < 4; ++i) {
        int ix = base + t * 4 + i;
        if (ix < NSEG) offs[ix] = run;
        run += v[i];
    }
    if (t == 255) bsum[blockIdx.x] = s[255];
}

__global__ __launch_bounds__(256)
void scan2_k(unsigned* __restrict__ bsum, int nb)
{
    __shared__ unsigned s[256];
    __shared__ unsigned carry;
    const int t = threadIdx.x;
    if (t == 0) carry = 0;
    __syncthreads();
    for (int base = 0; base < nb; base += 256) {
        unsigned v = (base + t < nb) ? bsum[base + t] : 0u;
        s[t] = v; __syncthreads();
        for (int off = 1; off < 256; off <<= 1) {
            unsigned x = (t >= off) ? s[t - off] : 0u;
            __syncthreads();
            s[t] += x;
            __syncthreads();
        }
        unsigned tot = s[255];
        unsigned excl = s[t] - v + carry;
        if (base + t < nb) bsum[base + t] = excl;
        __syncthreads();
        if (t == 0) carry += tot;
        __syncthreads();
    }
}

__global__ __launch_bounds__(256)
void scan3_k(unsigned* __restrict__ offs, const unsigned* __restrict__ bsum)
{
    const int base = blockIdx.x * 1024;
    unsigned add = bsum[blockIdx.x];
#pragma unroll
    for (int i = 0; i < 4; ++i) {
        int ix = base + threadIdx.x * 4 + i;
        if (ix < NSEG) offs[ix] += add;
    }
    if (blockIdx.x == 0 && threadIdx.x == 0) offs[NSEG] = NETOT;
}

__global__ __launch_bounds__(256)
void fill_k(const int* __restrict__ edge_src, const int* __restrict__ edge_dst,
            const float* __restrict__ edge_val,
            const unsigned* __restrict__ offs,
            const unsigned char* __restrict__ rank,
            int2* __restrict__ recs)
{
    int g = blockIdx.x * 256 + threadIdx.x;
    int r = g / NE;
    int src = edge_src[g];
    int seg = r * N_ENT + src;
    unsigned pos = offs[seg] + rank[g];
    int2 rec;
    rec.x = edge_dst[g];
    rec.y = __float_as_int(edge_val[g]);
    recs[pos] = rec;
}

// ---------------- FUSED: A[s] = sum_r segsum_r(emb)[s] @ K_r ----------------
// r9's proven kernel (4 waves, 32 rows, hoisted metadata, 3 staged slots +
// direct slot-3) with ONE change: cross-relation software pipelining by code
// motion. Loop order is now:
//   ISSUE(0); for j { drain+sync_a; consume(j)->X; tail; sync_b;
//                     ISSUE(j+1); M(j) }
// so relation j+1's gathers fly under M(j)'s MFMA work, and the wait lands
// at sync_a -- where the compiler emits a full vmcnt(0) drain anyway.
// All hazards covered by the two barriers (full vm+lgkm drains):
//   gbuf WAR: consume(j) ds_reads retired at sync_b before ISSUE(j+1) writes.
//   X RAW: consume->M via sync_b.  X WAR: M(j)->consume(j+1) via sync_a.
// No counted waits. sched_barrier(0) after ISSUE pins the glds issue point.
__global__ __launch_bounds__(256)
void fuse_k(const unsigned* __restrict__ offs, const int2* __restrict__ recs,
            const float* __restrict__ emb,
            const short* __restrict__ Kth, const short* __restrict__ Ktl,
            float* __restrict__ A)
{
    __shared__ float X[32][132];      // 16,896 B
    __shared__ float gbuf[4][3072];   // 49,152 B: per-wave 12 chunks x 256 floats

    const int t     = threadIdx.x;
    const int wv    = t >> 6;
    const int lane  = t & 63;
    const int col16 = lane & 15;
    const int g     = lane >> 4;
    const int s0    = blockIdx.x * 32;       // grid exact: N_ENT/32 = 3125
    const int mrow  = (wv >> 1) * 16;        // wave's MFMA row origin
    const int ccol  = (wv & 1) * 64;         // wave's MFMA col origin

    // ---- hoisted metadata: lane covers (rel = lane>>3, row = lane&7) ----
    const int mrel = lane >> 3, mr = lane & 7;
    const size_t seg = (size_t)mrel * N_ENT + (size_t)(s0 + wv * 8 + mr);
    const unsigned o_lo = offs[seg];
    const unsigned o_hi = offs[seg + 1];
    const int n = (int)(o_hi - o_lo);
    int2 rc[4];
#pragma unroll
    for (int p = 0; p < 4; ++p) {            // clamped, unconditional (proven)
        int ii = (p < n) ? p : (n - 1);
        if (ii < 0) ii = 0;
        unsigned pos = o_lo + (unsigned)ii;
        if (pos > (unsigned)(NETOT - 1)) pos = NETOT - 1;
        rc[p] = recs[pos];
    }

    f32x4 acc[4];
#pragma unroll
    for (int c = 0; c < 4; ++c) acc[c] = (f32x4){0.f, 0.f, 0.f, 0.f};

    float* gb = &gbuf[wv][0];

    // issue the 12 glds16 for relation jj (entries e=row*3+slot, 2 rows/instr)
    auto ISSUE = [&](int jj) {
        const int base = jj << 3;
#pragma unroll
        for (int i = 0; i < 12; ++i) {
            const int eA = 2 * i,      eB = 2 * i + 1;
            const int rwA = eA / 3,    slA = eA % 3;   // compile-time
            const int rwB = eB / 3,    slB = eB % 3;
            int dA = __shfl(rc[slA].x, base + rwA);
            int dB = __shfl(rc[slB].x, base + rwB);
            int d = (lane < 32) ? dA : dB;
            glds16(emb + (size_t)d * 128 + (lane & 31) * 4, gb + i * 256);
        }
        __builtin_amdgcn_sched_barrier(0);   // pin issue point
    };

    ISSUE(0);

    for (int j = 0; j < RR; ++j) {
        const int base = j << 3;

        // sync_a: gathers for j landed (full vmcnt drain at barrier); X free
        asm volatile("s_waitcnt vmcnt(0)" ::: "memory");
        __builtin_amdgcn_sched_barrier(0);
        __syncthreads();

        // ---- consume: 8 rows x slots 0..2 (LDS), slot 3 direct, tail rare --
        unsigned tailmask = 0;
#pragma unroll
        for (int row = 0; row < 8; ++row) {
            int nn = __shfl(n, base + row);  // wave-uniform per row
            float a0 = 0.f, a1 = 0.f;
#pragma unroll
            for (int sl = 0; sl < 3; ++sl) {
                const int e = row * 3 + sl;
                float vv = __uint_as_float((unsigned)__shfl(rc[sl].y, base + row));
                float v = (sl < nn) ? vv : 0.f;
                const float* yp = gb + (e >> 1) * 256 + (e & 1) * 128 + lane * 2;
                a0 = fmaf(v, yp[0], a0);
                a1 = fmaf(v, yp[1], a1);
            }
            if (nn > 3) {                    // wave-uniform, ~14% of rows
                int d4 = __shfl(rc[3].x, base + row);
                float v4 = __uint_as_float((unsigned)__shfl(rc[3].y, base + row));
                float2 y4 = *(const float2*)(emb + (size_t)d4 * 128 + lane * 2);
                a0 = fmaf(v4, y4.x, a0);
                a1 = fmaf(v4, y4.y, a1);
            }
            *(float2*)&X[wv * 8 + row][lane * 2] = (float2){a0, a1};
            if (nn > 4) tailmask |= (1u << row);
        }

        while (tailmask) {                   // n>4: ~1.4% of rows
            int row = __builtin_ctz(tailmask);
            tailmask &= tailmask - 1;
            unsigned aa = __shfl(o_lo, base + row);
            int nn = __shfl(n, base + row);
            float2 xv = *(float2*)&X[wv * 8 + row][lane * 2];
            for (int i2 = 4; i2 < nn; ++i2) {
                int2 rc2 = recs[aa + (unsigned)i2];
                float v = __int_as_float(rc2.y);
                float2 yy = *(const float2*)(emb + (size_t)rc2.x * 128 + lane * 2);
                xv.x = fmaf(v, yy.x, xv.x);
                xv.y = fmaf(v, yy.y, xv.y);
            }
            *(float2*)&X[wv * 8 + row][lane * 2] = xv;
        }

        // sync_b: X ready for all waves; gbuf reads retired (lgkm drain)
        __syncthreads();

        // ---- issue next relation's gathers; they fly under M(j) ----
        if (j + 1 < RR) ISSUE(j + 1);

        // ---- M phase: acc += X @ K_j (wave's 16x64 quadrant) ----
        const short* KH = Kth + (size_t)j * 16384;
        const short* KL = Ktl + (size_t)j * 16384;
#pragma unroll
        for (int s = 0; s < 4; ++s) {
            s16x8 bh[4], bl[4];
#pragma unroll
            for (int c = 0; c < 4; ++c) {
                int oo = ccol + c * 16 + col16;
                int k = s * 32 + g * 8;
                bh[c] = *(const s16x8*)(KH + (size_t)oo * 128 + k);
                bl[c] = *(const s16x8*)(KL + (size_t)oo * 128 + k);
            }
            const float* xp = &X[mrow + col16][s * 32 + g * 8];
            float4 u0 = *(const float4*)xp;
            float4 u1 = *(const float4*)(xp + 4);
            float u[8] = {u0.x, u0.y, u0.z, u0.w, u1.x, u1.y, u1.z, u1.w};
            s16x8 ah, al;
#pragma unroll
            for (int q = 0; q < 8; ++q) {
                short h, l; split2(u[q], h, l);
                ah[q] = h; al[q] = l;
            }
#pragma unroll
            for (int c = 0; c < 4; ++c) {
                acc[c] = __builtin_amdgcn_mfma_f32_16x16x32_bf16(ah, bh[c], acc[c], 0, 0, 0);
                acc[c] = __builtin_amdgcn_mfma_f32_16x16x32_bf16(ah, bl[c], acc[c], 0, 0, 0);
                acc[c] = __builtin_amdgcn_mfma_f32_16x16x32_bf16(al, bh[c], acc[c], 0, 0, 0);
            }
        }
    }

    // ---- epilogue: single A write (C layout: col=lane&15, row=g*4+reg) ----
#pragma unroll
    for (int jj = 0; jj < 4; ++jj) {
        int row = s0 + mrow + g * 4 + jj;
        float* op = A + (size_t)row * 128 + ccol;
#pragma unroll
        for (int c = 0; c < 4; ++c)
            op[c * 16 + col16] = acc[c][jj];
    }
}

extern "C" void kernel_launch(void* const* d_in, const int* in_sizes, int n_in,
                              void* d_out, int out_size, void* d_ws, size_t ws_size,
                              hipStream_t stream)
{
    const float* emb      = (const float*)d_in[0];
    const float* head_e   = (const float*)d_in[1];
    const float* tail_e   = (const float*)d_in[2];
    const float* rel_k    = (const float*)d_in[3];
    const float* self_k   = (const float*)d_in[4];
    const float* edge_val = (const float*)d_in[5];
    const int*   head_idx = (const int*)d_in[6];
    const int*   tail_idx = (const int*)d_in[7];
    const int*   edge_src = (const int*)d_in[8];
    const int*   edge_dst = (const int*)d_in[9];
    float* out = (float*)d_out;

    // workspace layout (each region 256B-aligned)
    char* p = (char*)d_ws;
    auto take = [&](size_t bytes) -> char* {
        char* q = p; p += (bytes + 255) & ~(size_t)255; return q;
    };
    float*         A    = (float*)take((size_t)N_ENT * 128 * sizeof(float));     // 51.2 MB
    int2*          recs = (int2*)take((size_t)NETOT * sizeof(int2));             // 12.8 MB
    unsigned*      cnt  = (unsigned*)take((size_t)NSEG * sizeof(unsigned));      //  3.2 MB
    unsigned*      offs = (unsigned*)take(((size_t)NSEG + 1) * sizeof(unsigned));//  3.2 MB
    unsigned*      bsum = (unsigned*)take(1024 * sizeof(unsigned));
    unsigned char* rank = (unsigned char*)take((size_t)NETOT);                   //  1.6 MB
    short*         Kth  = (short*)take((size_t)9 * 16384 * sizeof(short));       //  0.3 MB
    short*         Ktl  = (short*)take((size_t)9 * 16384 * sizeof(short));       //  0.3 MB

    const int NB1 = (NSEG + 1023) / 1024;     // 782
    dim3 blk(256);

    // ---- K transform + CSR build ----
    ktconv_k<<<9, blk, 0, stream>>>(rel_k, self_k, Kth, Ktl);
    hipMemsetAsync(cnt, 0, (size_t)NSEG * sizeof(unsigned), stream);
    count_k<<<NETOT / 256, blk, 0, stream>>>(edge_src, cnt, rank);
    scan1_k<<<NB1, blk, 0, stream>>>(cnt, offs, bsum);
    scan2_k<<<1, blk, 0, stream>>>(bsum, NB1);
    scan3_k<<<NB1, blk, 0, stream>>>(offs, bsum);
    fill_k<<<NETOT / 256, blk, 0, stream>>>(edge_src, edge_dst, edge_val,
                                            offs, rank, recs);

    // ---- fused aggregate + transform: A = sum_r segsum_r(emb) @ K_r ----
    const int gf = N_ENT / 32;                // 3125, exact
    fuse_k<<<gf, blk, 0, stream>>>(offs, recs, emb, Kth, Ktl, A);

    // ---- final: out = sigmoid(X @ S + A[idx]) ----
    const int gb = (NB + 127) / 128;          // 391
    gemm_mfma_k<true, false><<<gb, blk, 0, stream>>>(
        head_e, 128, Kth + (size_t)8 * 16384, Ktl + (size_t)8 * 16384, 1,
        A, head_idx, out, NB);
    gemm_mfma_k<true, false><<<gb, blk, 0, stream>>>(
        tail_e, 128, Kth + (size_t)8 * 16384, Ktl + (size_t)8 * 16384, 1,
        A, tail_idx, out + (size_t)NB * 128, NB);
}